// Round 1
// baseline (247.240 us; speedup 1.0000x reference)
//
#include <hip/hip_runtime.h>
#include <hip/hip_bf16.h>

typedef __attribute__((ext_vector_type(8))) __bf16 bf16x8;
typedef __attribute__((ext_vector_type(4))) __bf16 bf16x4;
typedef __attribute__((ext_vector_type(4))) float f32x4;

#define D_MODEL 768
#define SEQ     4096
#define NH      12
#define HD      64

// ---------------------------------------------------------------------------
// Kernel 0: fp32 -> bf16 conversion for x and the 4 weight matrices
// ---------------------------------------------------------------------------
__global__ __launch_bounds__(256) void cvt_kernel(
    const float* __restrict__ x,  const float* __restrict__ wq,
    const float* __restrict__ wk, const float* __restrict__ wv,
    const float* __restrict__ wo,
    __bf16* __restrict__ xb,  __bf16* __restrict__ wqb,
    __bf16* __restrict__ wkb, __bf16* __restrict__ wvb,
    __bf16* __restrict__ wob)
{
    const int XV = SEQ * D_MODEL / 4;        // 786432 float4s
    const int WV = D_MODEL * D_MODEL / 4;    // 147456 float4s
    const int total = XV + 4 * WV;
    for (int i = blockIdx.x * blockDim.x + threadIdx.x; i < total;
         i += gridDim.x * blockDim.x) {
        const float* src; __bf16* dst; int j;
        if      (i < XV)          { src = x;  dst = xb;  j = i; }
        else if (i < XV + WV)     { src = wq; dst = wqb; j = i - XV; }
        else if (i < XV + 2*WV)   { src = wk; dst = wkb; j = i - XV - WV; }
        else if (i < XV + 3*WV)   { src = wv; dst = wvb; j = i - XV - 2*WV; }
        else                      { src = wo; dst = wob; j = i - XV - 3*WV; }
        float4 v = ((const float4*)src)[j];
        bf16x4 o;
        o[0] = (__bf16)v.x; o[1] = (__bf16)v.y;
        o[2] = (__bf16)v.z; o[3] = (__bf16)v.w;
        ((bf16x4*)dst)[j] = o;
    }
}

// ---------------------------------------------------------------------------
// Shared 128x128 BT-GEMM core: C[m,n] = sum_k A[m,k] * B[n,k]
// A, B already offset to this block's 128-row panels. BK=32, 4 waves.
// ---------------------------------------------------------------------------
__device__ __forceinline__ void gemm128_core(
    const __bf16* __restrict__ A, const __bf16* __restrict__ B, int K,
    f32x4 acc[4][4], __bf16 (*As)[40], __bf16 (*Bs)[40])
{
    const int t = threadIdx.x;
    const int lane = t & 63, wid = t >> 6;
    const int wm = (wid & 1) * 64, wn = (wid >> 1) * 64;
    const int lr = lane & 15, lc = lane >> 4;

    for (int kt = 0; kt < K / 32; ++kt) {
        __syncthreads();
        #pragma unroll
        for (int i = 0; i < 2; ++i) {
            int L = t + i * 256;
            int row = L >> 2, c8 = (L & 3) * 8;
            *(bf16x8*)&As[row][c8] =
                *(const bf16x8*)&A[(size_t)row * K + kt * 32 + c8];
            *(bf16x8*)&Bs[row][c8] =
                *(const bf16x8*)&B[(size_t)row * K + kt * 32 + c8];
        }
        __syncthreads();
        bf16x8 af[4], bfr[4];
        #pragma unroll
        for (int mi = 0; mi < 4; ++mi)
            af[mi] = *(const bf16x8*)&As[wm + mi * 16 + lr][lc * 8];
        #pragma unroll
        for (int ni = 0; ni < 4; ++ni)
            bfr[ni] = *(const bf16x8*)&Bs[wn + ni * 16 + lr][lc * 8];
        #pragma unroll
        for (int mi = 0; mi < 4; ++mi)
            #pragma unroll
            for (int ni = 0; ni < 4; ++ni)
                acc[mi][ni] = __builtin_amdgcn_mfma_f32_16x16x32_bf16(
                    af[mi], bfr[ni], acc[mi][ni], 0, 0, 0);
    }
}

// ---------------------------------------------------------------------------
// Kernel 1: fused QKV projection. grid = (32, 18): y in [0,6)->Q, [6,12)->K,
// [12,18)->V (stored transposed [768][4096] for the attention PV step).
// ---------------------------------------------------------------------------
__global__ __launch_bounds__(256) void qkv_gemm(
    const __bf16* __restrict__ xb,
    const __bf16* __restrict__ wqb, const __bf16* __restrict__ wkb,
    const __bf16* __restrict__ wvb,
    const float* __restrict__ bq, const float* __restrict__ bk,
    const float* __restrict__ bv,
    __bf16* __restrict__ Qo, __bf16* __restrict__ Ko,
    __bf16* __restrict__ Vto)
{
    __shared__ __bf16 As[128][40];
    __shared__ __bf16 Bs[128][40];
    const int bm = blockIdx.x;
    const int seg = blockIdx.y / 6, bn = blockIdx.y % 6;
    const __bf16* B  = (seg == 0) ? wqb : (seg == 1) ? wkb : wvb;
    const float* bias = (seg == 0) ? bq : (seg == 1) ? bk : bv;

    f32x4 acc[4][4] = {};
    gemm128_core(xb + (size_t)bm * 128 * D_MODEL,
                 B  + (size_t)bn * 128 * D_MODEL, D_MODEL, acc, As, Bs);

    const int t = threadIdx.x, lane = t & 63, wid = t >> 6;
    const int wm = (wid & 1) * 64, wn = (wid >> 1) * 64;
    const int lr = lane & 15, lc = lane >> 4;
    const int m0 = bm * 128 + wm, n0 = bn * 128 + wn;

    if (seg < 2) {
        __bf16* O = (seg == 0) ? Qo : Ko;
        #pragma unroll
        for (int mi = 0; mi < 4; ++mi)
            #pragma unroll
            for (int ni = 0; ni < 4; ++ni) {
                int col = n0 + ni * 16 + lr;
                float bb = bias[col];
                #pragma unroll
                for (int r = 0; r < 4; ++r)
                    O[(size_t)(m0 + mi * 16 + lc * 4 + r) * D_MODEL + col] =
                        (__bf16)(acc[mi][ni][r] + bb);
            }
    } else {
        #pragma unroll
        for (int mi = 0; mi < 4; ++mi)
            #pragma unroll
            for (int ni = 0; ni < 4; ++ni) {
                int col = n0 + ni * 16 + lr;
                float bb = bias[col];
                bf16x4 pk;
                #pragma unroll
                for (int r = 0; r < 4; ++r)
                    pk[r] = (__bf16)(acc[mi][ni][r] + bb);
                *(bf16x4*)&Vto[(size_t)col * SEQ + m0 + mi * 16 + lc * 4] = pk;
            }
    }
}

// ---------------------------------------------------------------------------
// Kernel 2: flash attention. grid = (64 q-blocks, 12 heads), 4 waves/block,
// each wave owns 16 q-rows. KVBLK = 64. Q in registers; K, V^T in padded LDS.
// ---------------------------------------------------------------------------
__global__ __launch_bounds__(256) void attn_kernel(
    const __bf16* __restrict__ Q, const __bf16* __restrict__ K,
    const __bf16* __restrict__ Vt, __bf16* __restrict__ Attn)
{
    __shared__ __bf16 Ks[64][72];   // [kj][d]
    __shared__ __bf16 Vs[64][72];   // [d][kj]  (V transposed)
    __shared__ __bf16 Ps[4][16][72]; // per-wave P tile [qi][kj]

    const int h = blockIdx.y;
    const int q0 = blockIdx.x * 64;
    const int t = threadIdx.x, lane = t & 63, wid = t >> 6;
    const int lr = lane & 15, lc = lane >> 4;

    // Q fragments for this wave's 16 rows (K-chunks d=0..31, 32..63)
    const __bf16* qrow = Q + (size_t)(q0 + wid * 16 + lr) * D_MODEL + h * HD;
    bf16x8 qf0 = *(const bf16x8*)&qrow[lc * 8];
    bf16x8 qf1 = *(const bf16x8*)&qrow[32 + lc * 8];

    f32x4 acc[4] = {};        // O tiles over d (4 x 16 cols)
    float m_r[4], l_r[4];
    #pragma unroll
    for (int r = 0; r < 4; ++r) { m_r[r] = -1e30f; l_r[r] = 0.f; }

    for (int kt = 0; kt < SEQ / 64; ++kt) {
        __syncthreads();
        #pragma unroll
        for (int i = 0; i < 2; ++i) {
            int L = t + i * 256;
            int rr = L >> 3, c8 = (L & 7) * 8;
            *(bf16x8*)&Ks[rr][c8] =
                *(const bf16x8*)&K[(size_t)(kt * 64 + rr) * D_MODEL + h * HD + c8];
            *(bf16x8*)&Vs[rr][c8] =
                *(const bf16x8*)&Vt[(size_t)(h * HD + rr) * SEQ + kt * 64 + c8];
        }
        __syncthreads();

        // S = Q K^T * scale
        f32x4 st[4];
        #pragma unroll
        for (int nt = 0; nt < 4; ++nt) {
            f32x4 s = {};
            bf16x8 kf0 = *(const bf16x8*)&Ks[nt * 16 + lr][lc * 8];
            bf16x8 kf1 = *(const bf16x8*)&Ks[nt * 16 + lr][32 + lc * 8];
            s = __builtin_amdgcn_mfma_f32_16x16x32_bf16(qf0, kf0, s, 0, 0, 0);
            s = __builtin_amdgcn_mfma_f32_16x16x32_bf16(qf1, kf1, s, 0, 0, 0);
            st[nt] = s;
        }
        #pragma unroll
        for (int nt = 0; nt < 4; ++nt)
            #pragma unroll
            for (int r = 0; r < 4; ++r)
                st[nt][r] *= 0.125f;

        // online softmax per q-row r
        #pragma unroll
        for (int r = 0; r < 4; ++r) {
            float mx = fmaxf(fmaxf(st[0][r], st[1][r]),
                             fmaxf(st[2][r], st[3][r]));
            #pragma unroll
            for (int off = 1; off < 16; off <<= 1)
                mx = fmaxf(mx, __shfl_xor(mx, off, 64));
            float mnew = fmaxf(m_r[r], mx);
            float corr = __expf(m_r[r] - mnew);
            float rs = 0.f;
            #pragma unroll
            for (int nt = 0; nt < 4; ++nt) {
                float p = __expf(st[nt][r] - mnew);
                st[nt][r] = p;
                rs += p;
            }
            #pragma unroll
            for (int off = 1; off < 16; off <<= 1)
                rs += __shfl_xor(rs, off, 64);
            l_r[r] = l_r[r] * corr + rs;
            m_r[r] = mnew;
            #pragma unroll
            for (int dt = 0; dt < 4; ++dt)
                acc[dt][r] *= corr;
        }

        // P -> per-wave LDS (re-layout for A-fragment)
        #pragma unroll
        for (int nt = 0; nt < 4; ++nt)
            #pragma unroll
            for (int r = 0; r < 4; ++r)
                Ps[wid][lc * 4 + r][nt * 16 + lr] = (__bf16)st[nt][r];

        // O += P V
        bf16x8 pa0 = *(const bf16x8*)&Ps[wid][lr][lc * 8];
        bf16x8 pa1 = *(const bf16x8*)&Ps[wid][lr][32 + lc * 8];
        #pragma unroll
        for (int dt = 0; dt < 4; ++dt) {
            bf16x8 vf0 = *(const bf16x8*)&Vs[dt * 16 + lr][lc * 8];
            bf16x8 vf1 = *(const bf16x8*)&Vs[dt * 16 + lr][32 + lc * 8];
            acc[dt] = __builtin_amdgcn_mfma_f32_16x16x32_bf16(pa0, vf0, acc[dt], 0, 0, 0);
            acc[dt] = __builtin_amdgcn_mfma_f32_16x16x32_bf16(pa1, vf1, acc[dt], 0, 0, 0);
        }
    }

    // epilogue: O / l -> attn buffer [S][768] (head-concat layout)
    #pragma unroll
    for (int dt = 0; dt < 4; ++dt)
        #pragma unroll
        for (int r = 0; r < 4; ++r) {
            float o = acc[dt][r] / l_r[r];
            Attn[(size_t)(q0 + wid * 16 + lc * 4 + r) * D_MODEL
                 + h * HD + dt * 16 + lr] = (__bf16)o;
        }
}

// ---------------------------------------------------------------------------
// Kernel 3: output projection -> fp32 d_out
// ---------------------------------------------------------------------------
__global__ __launch_bounds__(256) void out_gemm(
    const __bf16* __restrict__ Ab, const __bf16* __restrict__ wob,
    const float* __restrict__ bo, float* __restrict__ out)
{
    __shared__ __bf16 As[128][40];
    __shared__ __bf16 Bs[128][40];
    const int bm = blockIdx.x, bn = blockIdx.y;
    f32x4 acc[4][4] = {};
    gemm128_core(Ab  + (size_t)bm * 128 * D_MODEL,
                 wob + (size_t)bn * 128 * D_MODEL, D_MODEL, acc, As, Bs);

    const int t = threadIdx.x, lane = t & 63, wid = t >> 6;
    const int wm = (wid & 1) * 64, wn = (wid >> 1) * 64;
    const int lr = lane & 15, lc = lane >> 4;
    const int m0 = bm * 128 + wm, n0 = bn * 128 + wn;
    #pragma unroll
    for (int mi = 0; mi < 4; ++mi)
        #pragma unroll
        for (int ni = 0; ni < 4; ++ni) {
            int col = n0 + ni * 16 + lr;
            float bb = bo[col];
            #pragma unroll
            for (int r = 0; r < 4; ++r)
                out[(size_t)(m0 + mi * 16 + lc * 4 + r) * D_MODEL + col] =
                    acc[mi][ni][r] + bb;
        }
}

// ---------------------------------------------------------------------------
extern "C" void kernel_launch(void* const* d_in, const int* in_sizes, int n_in,
                              void* d_out, int out_size, void* d_ws, size_t ws_size,
                              hipStream_t stream) {
    const float* x  = (const float*)d_in[0];
    const float* wq = (const float*)d_in[1];
    const float* bq = (const float*)d_in[2];
    const float* wk = (const float*)d_in[3];
    const float* bk = (const float*)d_in[4];
    const float* wv = (const float*)d_in[5];
    const float* bv = (const float*)d_in[6];
    const float* wo = (const float*)d_in[7];
    const float* bo = (const float*)d_in[8];

    char* ws = (char*)d_ws;
    const size_t XB_SZ = (size_t)SEQ * D_MODEL * 2;      // 6291456
    const size_t W_SZ  = (size_t)D_MODEL * D_MODEL * 2;  // 1179648
    __bf16* xb  = (__bf16*)(ws);
    __bf16* wqb = (__bf16*)(ws + XB_SZ);
    __bf16* wkb = (__bf16*)(ws + XB_SZ + W_SZ);
    __bf16* wvb = (__bf16*)(ws + XB_SZ + 2 * W_SZ);
    __bf16* wob = (__bf16*)(ws + XB_SZ + 3 * W_SZ);
    __bf16* Qb  = (__bf16*)(ws + XB_SZ + 4 * W_SZ);
    __bf16* Kb  = (__bf16*)(ws + 2 * XB_SZ + 4 * W_SZ);
    __bf16* Vtb = (__bf16*)(ws + 3 * XB_SZ + 4 * W_SZ);
    __bf16* Ab  = (__bf16*)(ws + 4 * XB_SZ + 4 * W_SZ);

    cvt_kernel<<<1024, 256, 0, stream>>>(x, wq, wk, wv, wo,
                                         xb, wqb, wkb, wvb, wob);
    qkv_gemm<<<dim3(32, 18), 256, 0, stream>>>(xb, wqb, wkb, wvb,
                                               bq, bk, bv, Qb, Kb, Vtb);
    attn_kernel<<<dim3(64, 12), 256, 0, stream>>>(Qb, Kb, Vtb, Ab);
    out_gemm<<<dim3(32, 6), 256, 0, stream>>>(Ab, wob, bo, (float*)d_out);
}

// Round 2
// 191.117 us; speedup vs baseline: 1.2937x; 1.2937x over previous
//
#include <hip/hip_runtime.h>
#include <hip/hip_bf16.h>

typedef __attribute__((ext_vector_type(8))) __bf16 bf16x8;
typedef __attribute__((ext_vector_type(4))) __bf16 bf16x4;
typedef __attribute__((ext_vector_type(4))) float f32x4;

#define D_MODEL 768
#define SEQ     4096
#define NH      12
#define HD      64

// ---------------------------------------------------------------------------
// Kernel 0: fp32 -> bf16 conversion for x and the 4 weight matrices
// ---------------------------------------------------------------------------
__global__ __launch_bounds__(256) void cvt_kernel(
    const float* __restrict__ x,  const float* __restrict__ wq,
    const float* __restrict__ wk, const float* __restrict__ wv,
    const float* __restrict__ wo,
    __bf16* __restrict__ xb,  __bf16* __restrict__ wqb,
    __bf16* __restrict__ wkb, __bf16* __restrict__ wvb,
    __bf16* __restrict__ wob)
{
    const int XV = SEQ * D_MODEL / 4;
    const int WV = D_MODEL * D_MODEL / 4;
    const int total = XV + 4 * WV;
    for (int i = blockIdx.x * blockDim.x + threadIdx.x; i < total;
         i += gridDim.x * blockDim.x) {
        const float* src; __bf16* dst; int j;
        if      (i < XV)          { src = x;  dst = xb;  j = i; }
        else if (i < XV + WV)     { src = wq; dst = wqb; j = i - XV; }
        else if (i < XV + 2*WV)   { src = wk; dst = wkb; j = i - XV - WV; }
        else if (i < XV + 3*WV)   { src = wv; dst = wvb; j = i - XV - 2*WV; }
        else                      { src = wo; dst = wob; j = i - XV - 3*WV; }
        float4 v = ((const float4*)src)[j];
        bf16x4 o;
        o[0] = (__bf16)v.x; o[1] = (__bf16)v.y;
        o[2] = (__bf16)v.z; o[3] = (__bf16)v.w;
        ((bf16x4*)dst)[j] = o;
    }
}

// ---------------------------------------------------------------------------
// Shared 128x128 BT-GEMM core: C[m,n] = sum_k A[m,k] * B[n,k]
// ---------------------------------------------------------------------------
__device__ __forceinline__ void gemm128_core(
    const __bf16* __restrict__ A, const __bf16* __restrict__ B, int K,
    f32x4 acc[4][4], __bf16 (*As)[40], __bf16 (*Bs)[40])
{
    const int t = threadIdx.x;
    const int lane = t & 63, wid = t >> 6;
    const int wm = (wid & 1) * 64, wn = (wid >> 1) * 64;
    const int lr = lane & 15, lc = lane >> 4;

    for (int kt = 0; kt < K / 32; ++kt) {
        __syncthreads();
        #pragma unroll
        for (int i = 0; i < 2; ++i) {
            int L = t + i * 256;
            int row = L >> 2, c8 = (L & 3) * 8;
            *(bf16x8*)&As[row][c8] =
                *(const bf16x8*)&A[(size_t)row * K + kt * 32 + c8];
            *(bf16x8*)&Bs[row][c8] =
                *(const bf16x8*)&B[(size_t)row * K + kt * 32 + c8];
        }
        __syncthreads();
        bf16x8 af[4], bfr[4];
        #pragma unroll
        for (int mi = 0; mi < 4; ++mi)
            af[mi] = *(const bf16x8*)&As[wm + mi * 16 + lr][lc * 8];
        #pragma unroll
        for (int ni = 0; ni < 4; ++ni)
            bfr[ni] = *(const bf16x8*)&Bs[wn + ni * 16 + lr][lc * 8];
        #pragma unroll
        for (int mi = 0; mi < 4; ++mi)
            #pragma unroll
            for (int ni = 0; ni < 4; ++ni)
                acc[mi][ni] = __builtin_amdgcn_mfma_f32_16x16x32_bf16(
                    af[mi], bfr[ni], acc[mi][ni], 0, 0, 0);
    }
}

// ---------------------------------------------------------------------------
// Kernel 1: fused QKV projection.
// ---------------------------------------------------------------------------
__global__ __launch_bounds__(256) void qkv_gemm(
    const __bf16* __restrict__ xb,
    const __bf16* __restrict__ wqb, const __bf16* __restrict__ wkb,
    const __bf16* __restrict__ wvb,
    const float* __restrict__ bq, const float* __restrict__ bk,
    const float* __restrict__ bv,
    __bf16* __restrict__ Qo, __bf16* __restrict__ Ko,
    __bf16* __restrict__ Vto)
{
    __shared__ __bf16 As[128][40];
    __shared__ __bf16 Bs[128][40];
    const int bm = blockIdx.x;
    const int seg = blockIdx.y / 6, bn = blockIdx.y % 6;
    const __bf16* B  = (seg == 0) ? wqb : (seg == 1) ? wkb : wvb;
    const float* bias = (seg == 0) ? bq : (seg == 1) ? bk : bv;

    f32x4 acc[4][4] = {};
    gemm128_core(xb + (size_t)bm * 128 * D_MODEL,
                 B  + (size_t)bn * 128 * D_MODEL, D_MODEL, acc, As, Bs);

    const int t = threadIdx.x, lane = t & 63, wid = t >> 6;
    const int wm = (wid & 1) * 64, wn = (wid >> 1) * 64;
    const int lr = lane & 15, lc = lane >> 4;
    const int m0 = bm * 128 + wm, n0 = bn * 128 + wn;

    if (seg < 2) {
        __bf16* O = (seg == 0) ? Qo : Ko;
        #pragma unroll
        for (int mi = 0; mi < 4; ++mi)
            #pragma unroll
            for (int ni = 0; ni < 4; ++ni) {
                int col = n0 + ni * 16 + lr;
                float bb = bias[col];
                #pragma unroll
                for (int r = 0; r < 4; ++r)
                    O[(size_t)(m0 + mi * 16 + lc * 4 + r) * D_MODEL + col] =
                        (__bf16)(acc[mi][ni][r] + bb);
            }
    } else {
        #pragma unroll
        for (int mi = 0; mi < 4; ++mi)
            #pragma unroll
            for (int ni = 0; ni < 4; ++ni) {
                int col = n0 + ni * 16 + lr;
                float bb = bias[col];
                bf16x4 pk;
                #pragma unroll
                for (int r = 0; r < 4; ++r)
                    pk[r] = (__bf16)(acc[mi][ni][r] + bb);
                *(bf16x4*)&Vto[(size_t)col * SEQ + m0 + mi * 16 + lc * 4] = pk;
            }
    }
}

// ---------------------------------------------------------------------------
// Kernel 2: flash attention, swapped-QK^T + double-buffered K/V prefetch.
// grid = (64 q-blocks, 12 heads), 4 waves, wave owns 16 q-rows, KVBLK = 64.
// ---------------------------------------------------------------------------
__global__ __launch_bounds__(256) void attn_kernel(
    const __bf16* __restrict__ Q, const __bf16* __restrict__ K,
    const __bf16* __restrict__ Vt, __bf16* __restrict__ Attn)
{
    __shared__ __bf16 Ks[2][64][72];   // [buf][kv][d]
    __shared__ __bf16 Vs[2][64][72];   // [buf][d][kv]
    __shared__ __bf16 Ps[4][16][72];   // per-wave P [q][kv]

    const int h = blockIdx.y;
    const int q0 = blockIdx.x * 64;
    const int t = threadIdx.x, lane = t & 63, wid = t >> 6;
    const int lr = lane & 15, lc = lane >> 4;

    // staging addresses (per thread, 2 chunks)
    const int L0 = t, L1 = t + 256;
    const int r0 = L0 >> 3, c0 = (L0 & 7) * 8;
    const int r1 = L1 >> 3, c1 = (L1 & 7) * 8;

    // Q fragments (B-operand): lane holds Q[q=lr][d = lc*8..+7 (+32)]
    const __bf16* qrow = Q + (size_t)(q0 + wid * 16 + lr) * D_MODEL + h * HD;
    bf16x8 qf0 = *(const bf16x8*)&qrow[lc * 8];
    bf16x8 qf1 = *(const bf16x8*)&qrow[32 + lc * 8];

    f32x4 acc[4] = {};          // O[q = lc*4+r][d = dt*16 + lr]
    float m_r = -1e30f, l_r = 0.f;   // per-lane state for q-row = lr
    const float CS = 0.125f * 1.44269504088896f;  // scale * log2(e)

    // prologue: stage tile 0
    {
        bf16x8 ka = *(const bf16x8*)&K[(size_t)r0 * D_MODEL + h * HD + c0];
        bf16x8 kb = *(const bf16x8*)&K[(size_t)r1 * D_MODEL + h * HD + c1];
        bf16x8 va = *(const bf16x8*)&Vt[(size_t)(h * HD + r0) * SEQ + c0];
        bf16x8 vb = *(const bf16x8*)&Vt[(size_t)(h * HD + r1) * SEQ + c1];
        *(bf16x8*)&Ks[0][r0][c0] = ka;  *(bf16x8*)&Ks[0][r1][c1] = kb;
        *(bf16x8*)&Vs[0][r0][c0] = va;  *(bf16x8*)&Vs[0][r1][c1] = vb;
    }
    __syncthreads();

    for (int kt = 0; kt < SEQ / 64; ++kt) {
        const int cur = kt & 1, nxt = cur ^ 1;

        // issue next-tile global loads early (latency hidden under QK+softmax)
        bf16x8 ka, kb, va, vb;
        const bool pf = (kt + 1 < SEQ / 64);
        if (pf) {
            const size_t ko = (size_t)((kt + 1) * 64) * D_MODEL + h * HD;
            const size_t vo = (size_t)(h * HD) * SEQ + (kt + 1) * 64;
            ka = *(const bf16x8*)&K[ko + (size_t)r0 * D_MODEL + c0];
            kb = *(const bf16x8*)&K[ko + (size_t)r1 * D_MODEL + c1];
            va = *(const bf16x8*)&Vt[vo + (size_t)r0 * SEQ + c0];
            vb = *(const bf16x8*)&Vt[vo + (size_t)r1 * SEQ + c1];
        }

        // S^T = K Q^T : lane holds S[kv = nt*16 + lc*4 + r][q = lr]
        bf16x8 kf[4][2];
        #pragma unroll
        for (int nt = 0; nt < 4; ++nt) {
            kf[nt][0] = *(const bf16x8*)&Ks[cur][nt * 16 + lr][lc * 8];
            kf[nt][1] = *(const bf16x8*)&Ks[cur][nt * 16 + lr][32 + lc * 8];
        }
        f32x4 st[4];
        __builtin_amdgcn_s_setprio(1);
        #pragma unroll
        for (int nt = 0; nt < 4; ++nt) {
            f32x4 s = {};
            s = __builtin_amdgcn_mfma_f32_16x16x32_bf16(kf[nt][0], qf0, s, 0, 0, 0);
            s = __builtin_amdgcn_mfma_f32_16x16x32_bf16(kf[nt][1], qf1, s, 0, 0, 0);
            st[nt] = s;
        }
        __builtin_amdgcn_s_setprio(0);

        // ---- softmax (log2 domain), row q = lr fully lane-local ----
        float s2[4][4];
        float mx = -1e30f;
        #pragma unroll
        for (int nt = 0; nt < 4; ++nt)
            #pragma unroll
            for (int r = 0; r < 4; ++r) {
                float v = st[nt][r] * CS;
                s2[nt][r] = v;
                mx = fmaxf(mx, v);
            }
        mx = fmaxf(mx, __shfl_xor(mx, 16, 64));
        mx = fmaxf(mx, __shfl_xor(mx, 32, 64));

        const bool skip = (bool)__all(mx - m_r <= 8.0f);  // defer-max (T13)
        float mnew = skip ? m_r : fmaxf(m_r, mx);
        float corr = skip ? 1.0f : exp2f(m_r - mnew);

        float rs = 0.f;
        float pv[4][4];
        #pragma unroll
        for (int nt = 0; nt < 4; ++nt)
            #pragma unroll
            for (int r = 0; r < 4; ++r) {
                float p = exp2f(s2[nt][r] - mnew);
                pv[nt][r] = p;
                rs += p;
            }
        rs += __shfl_xor(rs, 16, 64);
        rs += __shfl_xor(rs, 32, 64);
        l_r = l_r * corr + rs;
        m_r = mnew;

        if (!skip) {
            #pragma unroll
            for (int r = 0; r < 4; ++r) {
                float cq = __shfl(corr, lc * 4 + r, 64);
                #pragma unroll
                for (int dt = 0; dt < 4; ++dt)
                    acc[dt][r] *= cq;
            }
        }

        // P -> per-wave LDS, packed u32 writes (row q = lr, col kv)
        #pragma unroll
        for (int nt = 0; nt < 4; ++nt) {
            union { __bf16 h2[2]; unsigned u; } w0, w1;
            w0.h2[0] = (__bf16)pv[nt][0]; w0.h2[1] = (__bf16)pv[nt][1];
            w1.h2[0] = (__bf16)pv[nt][2]; w1.h2[1] = (__bf16)pv[nt][3];
            *(unsigned*)&Ps[wid][lr][nt * 16 + lc * 4]     = w0.u;
            *(unsigned*)&Ps[wid][lr][nt * 16 + lc * 4 + 2] = w1.u;
        }

        // stage next tile into the other buffer (global loads have landed)
        if (pf) {
            *(bf16x8*)&Ks[nxt][r0][c0] = ka;  *(bf16x8*)&Ks[nxt][r1][c1] = kb;
            *(bf16x8*)&Vs[nxt][r0][c0] = va;  *(bf16x8*)&Vs[nxt][r1][c1] = vb;
        }

        // O += P V : A = P[q][kv], B = Vt[d][kv]
        bf16x8 pa0 = *(const bf16x8*)&Ps[wid][lr][lc * 8];
        bf16x8 pa1 = *(const bf16x8*)&Ps[wid][lr][32 + lc * 8];
        __builtin_amdgcn_s_setprio(1);
        #pragma unroll
        for (int dt = 0; dt < 4; ++dt) {
            bf16x8 vf0 = *(const bf16x8*)&Vs[cur][dt * 16 + lr][lc * 8];
            bf16x8 vf1 = *(const bf16x8*)&Vs[cur][dt * 16 + lr][32 + lc * 8];
            acc[dt] = __builtin_amdgcn_mfma_f32_16x16x32_bf16(pa0, vf0, acc[dt], 0, 0, 0);
            acc[dt] = __builtin_amdgcn_mfma_f32_16x16x32_bf16(pa1, vf1, acc[dt], 0, 0, 0);
        }
        __builtin_amdgcn_s_setprio(0);

        __syncthreads();
    }

    // epilogue: O / l  (l for q-row lc*4+r lives on lane lc*4+r)
    #pragma unroll
    for (int r = 0; r < 4; ++r) {
        float linv = 1.0f / __shfl(l_r, lc * 4 + r, 64);
        #pragma unroll
        for (int dt = 0; dt < 4; ++dt)
            Attn[(size_t)(q0 + wid * 16 + lc * 4 + r) * D_MODEL
                 + h * HD + dt * 16 + lr] = (__bf16)(acc[dt][r] * linv);
    }
}

// ---------------------------------------------------------------------------
// Kernel 3: output projection -> fp32 d_out
// ---------------------------------------------------------------------------
__global__ __launch_bounds__(256) void out_gemm(
    const __bf16* __restrict__ Ab, const __bf16* __restrict__ wob,
    const float* __restrict__ bo, float* __restrict__ out)
{
    __shared__ __bf16 As[128][40];
    __shared__ __bf16 Bs[128][40];
    const int bm = blockIdx.x, bn = blockIdx.y;
    f32x4 acc[4][4] = {};
    gemm128_core(Ab  + (size_t)bm * 128 * D_MODEL,
                 wob + (size_t)bn * 128 * D_MODEL, D_MODEL, acc, As, Bs);

    const int t = threadIdx.x, lane = t & 63, wid = t >> 6;
    const int wm = (wid & 1) * 64, wn = (wid >> 1) * 64;
    const int lr = lane & 15, lc = lane >> 4;
    const int m0 = bm * 128 + wm, n0 = bn * 128 + wn;
    #pragma unroll
    for (int mi = 0; mi < 4; ++mi)
        #pragma unroll
        for (int ni = 0; ni < 4; ++ni) {
            int col = n0 + ni * 16 + lr;
            float bb = bo[col];
            #pragma unroll
            for (int r = 0; r < 4; ++r)
                out[(size_t)(m0 + mi * 16 + lc * 4 + r) * D_MODEL + col] =
                    acc[mi][ni][r] + bb;
        }
}

// ---------------------------------------------------------------------------
extern "C" void kernel_launch(void* const* d_in, const int* in_sizes, int n_in,
                              void* d_out, int out_size, void* d_ws, size_t ws_size,
                              hipStream_t stream) {
    const float* x  = (const float*)d_in[0];
    const float* wq = (const float*)d_in[1];
    const float* bq = (const float*)d_in[2];
    const float* wk = (const float*)d_in[3];
    const float* bk = (const float*)d_in[4];
    const float* wv = (const float*)d_in[5];
    const float* bv = (const float*)d_in[6];
    const float* wo = (const float*)d_in[7];
    const float* bo = (const float*)d_in[8];

    char* ws = (char*)d_ws;
    const size_t XB_SZ = (size_t)SEQ * D_MODEL * 2;
    const size_t W_SZ  = (size_t)D_MODEL * D_MODEL * 2;
    __bf16* xb  = (__bf16*)(ws);
    __bf16* wqb = (__bf16*)(ws + XB_SZ);
    __bf16* wkb = (__bf16*)(ws + XB_SZ + W_SZ);
    __bf16* wvb = (__bf16*)(ws + XB_SZ + 2 * W_SZ);
    __bf16* wob = (__bf16*)(ws + XB_SZ + 3 * W_SZ);
    __bf16* Qb  = (__bf16*)(ws + XB_SZ + 4 * W_SZ);
    __bf16* Kb  = (__bf16*)(ws + 2 * XB_SZ + 4 * W_SZ);
    __bf16* Vtb = (__bf16*)(ws + 3 * XB_SZ + 4 * W_SZ);
    __bf16* Ab  = (__bf16*)(ws + 4 * XB_SZ + 4 * W_SZ);

    cvt_kernel<<<1024, 256, 0, stream>>>(x, wq, wk, wv, wo,
                                         xb, wqb, wkb, wvb, wob);
    qkv_gemm<<<dim3(32, 18), 256, 0, stream>>>(xb, wqb, wkb, wvb,
                                               bq, bk, bv, Qb, Kb, Vtb);
    attn_kernel<<<dim3(64, 12), 256, 0, stream>>>(Qb, Kb, Vtb, Ab);
    out_gemm<<<dim3(32, 6), 256, 0, stream>>>(Ab, wob, bo, (float*)d_out);
}

// Round 3
// 180.921 us; speedup vs baseline: 1.3666x; 1.0564x over previous
//
#include <hip/hip_runtime.h>
#include <hip/hip_bf16.h>

typedef __attribute__((ext_vector_type(8))) __bf16 bf16x8;
typedef __attribute__((ext_vector_type(4))) __bf16 bf16x4;
typedef __attribute__((ext_vector_type(4))) float f32x4;

#define D_MODEL 768
#define SEQ     4096
#define NH      12
#define HD      64

// scale * log2(e), folded into Q at projection time
#define QSCALE (0.125f * 1.44269504088896f)

__device__ __forceinline__ void gload_lds16(const void* g, void* l) {
    __builtin_amdgcn_global_load_lds(
        (const __attribute__((address_space(1))) void*)g,
        (__attribute__((address_space(3))) void*)l, 16, 0, 0);
}

// ---------------------------------------------------------------------------
// Kernel 0: fp32 -> bf16 conversion
// ---------------------------------------------------------------------------
__global__ __launch_bounds__(256) void cvt_kernel(
    const float* __restrict__ x,  const float* __restrict__ wq,
    const float* __restrict__ wk, const float* __restrict__ wv,
    const float* __restrict__ wo,
    __bf16* __restrict__ xb,  __bf16* __restrict__ wqb,
    __bf16* __restrict__ wkb, __bf16* __restrict__ wvb,
    __bf16* __restrict__ wob)
{
    const int XV = SEQ * D_MODEL / 4;
    const int WV = D_MODEL * D_MODEL / 4;
    const int total = XV + 4 * WV;
    for (int i = blockIdx.x * blockDim.x + threadIdx.x; i < total;
         i += gridDim.x * blockDim.x) {
        const float* src; __bf16* dst; int j;
        if      (i < XV)          { src = x;  dst = xb;  j = i; }
        else if (i < XV + WV)     { src = wq; dst = wqb; j = i - XV; }
        else if (i < XV + 2*WV)   { src = wk; dst = wkb; j = i - XV - WV; }
        else if (i < XV + 3*WV)   { src = wv; dst = wvb; j = i - XV - 2*WV; }
        else                      { src = wo; dst = wob; j = i - XV - 3*WV; }
        float4 v = ((const float4*)src)[j];
        bf16x4 o;
        o[0] = (__bf16)v.x; o[1] = (__bf16)v.y;
        o[2] = (__bf16)v.z; o[3] = (__bf16)v.w;
        ((bf16x4*)dst)[j] = o;
    }
}

// ---------------------------------------------------------------------------
// Shared 128x128 BT-GEMM core, BK=64, global_load_lds staging, XOR swizzle.
// C[m,n] = sum_k A[m,k]*B[n,k].  As/Bs are [128][64].
// ---------------------------------------------------------------------------
__device__ __forceinline__ void gemm128_core(
    const __bf16* __restrict__ A, const __bf16* __restrict__ B, int KD,
    f32x4 acc[4][4], __bf16 (*As)[64], __bf16 (*Bs)[64])
{
    const int t = threadIdx.x;
    const int lane = t & 63, wid = t >> 6;
    const int wm = (wid & 1) * 64, wn = (wid >> 1) * 64;
    const int lr = lane & 15, lc = lane >> 4;
    const int rl = lane >> 3;                 // 0..7
    const int cs = (lane & 7) ^ rl;           // swizzled source chunk

    const __bf16* ag = A + (size_t)(wid * 32 + rl) * KD + cs * 8;
    const __bf16* bg = B + (size_t)(wid * 32 + rl) * KD + cs * 8;

    for (int kt = 0; kt < KD / 64; ++kt) {
        __syncthreads();   // all waves done reading LDS from prev iter
        #pragma unroll
        for (int i = 0; i < 4; ++i) {
            gload_lds16(ag + (size_t)i * 8 * KD + kt * 64,
                        &As[wid * 32 + i * 8][0]);
            gload_lds16(bg + (size_t)i * 8 * KD + kt * 64,
                        &Bs[wid * 32 + i * 8][0]);
        }
        __syncthreads();   // implicit vmcnt(0) drain -> data visible

        #pragma unroll
        for (int kh = 0; kh < 2; ++kh) {
            bf16x8 af[4], bfr[4];
            #pragma unroll
            for (int mi = 0; mi < 4; ++mi)
                af[mi] = *(const bf16x8*)
                    &As[wm + mi * 16 + lr][(((kh << 2) | lc) ^ (lr & 7)) * 8];
            #pragma unroll
            for (int ni = 0; ni < 4; ++ni)
                bfr[ni] = *(const bf16x8*)
                    &Bs[wn + ni * 16 + lr][(((kh << 2) | lc) ^ (lr & 7)) * 8];
            __builtin_amdgcn_s_setprio(1);
            #pragma unroll
            for (int mi = 0; mi < 4; ++mi)
                #pragma unroll
                for (int ni = 0; ni < 4; ++ni)
                    acc[mi][ni] = __builtin_amdgcn_mfma_f32_16x16x32_bf16(
                        af[mi], bfr[ni], acc[mi][ni], 0, 0, 0);
            __builtin_amdgcn_s_setprio(0);
        }
    }
}

// ---------------------------------------------------------------------------
// Kernel 1: fused QKV projection. Q gets QSCALE folded in.
// ---------------------------------------------------------------------------
__global__ __launch_bounds__(256) void qkv_gemm(
    const __bf16* __restrict__ xb,
    const __bf16* __restrict__ wqb, const __bf16* __restrict__ wkb,
    const __bf16* __restrict__ wvb,
    const float* __restrict__ bq, const float* __restrict__ bk,
    const float* __restrict__ bv,
    __bf16* __restrict__ Qo, __bf16* __restrict__ Ko,
    __bf16* __restrict__ Vto)
{
    __shared__ __bf16 As[128][64];
    __shared__ __bf16 Bs[128][64];
    const int bm = blockIdx.x;
    const int seg = blockIdx.y / 6, bn = blockIdx.y % 6;
    const __bf16* B  = (seg == 0) ? wqb : (seg == 1) ? wkb : wvb;
    const float* bias = (seg == 0) ? bq : (seg == 1) ? bk : bv;

    f32x4 acc[4][4] = {};
    gemm128_core(xb + (size_t)bm * 128 * D_MODEL,
                 B  + (size_t)bn * 128 * D_MODEL, D_MODEL, acc, As, Bs);

    const int t = threadIdx.x, lane = t & 63, wid = t >> 6;
    const int wm = (wid & 1) * 64, wn = (wid >> 1) * 64;
    const int lr = lane & 15, lc = lane >> 4;
    const int m0 = bm * 128 + wm, n0 = bn * 128 + wn;

    if (seg < 2) {
        __bf16* O = (seg == 0) ? Qo : Ko;
        const float sc = (seg == 0) ? QSCALE : 1.0f;
        #pragma unroll
        for (int mi = 0; mi < 4; ++mi)
            #pragma unroll
            for (int ni = 0; ni < 4; ++ni) {
                int col = n0 + ni * 16 + lr;
                float bb = bias[col];
                #pragma unroll
                for (int r = 0; r < 4; ++r)
                    O[(size_t)(m0 + mi * 16 + lc * 4 + r) * D_MODEL + col] =
                        (__bf16)((acc[mi][ni][r] + bb) * sc);
            }
    } else {
        #pragma unroll
        for (int mi = 0; mi < 4; ++mi)
            #pragma unroll
            for (int ni = 0; ni < 4; ++ni) {
                int col = n0 + ni * 16 + lr;
                float bb = bias[col];
                bf16x4 pk;
                #pragma unroll
                for (int r = 0; r < 4; ++r)
                    pk[r] = (__bf16)(acc[mi][ni][r] + bb);
                *(bf16x4*)&Vto[(size_t)col * SEQ + m0 + mi * 16 + lc * 4] = pk;
            }
    }
}

// ---------------------------------------------------------------------------
// Kernel 2: flash attention. 1D grid 768 blocks (XCD-swizzled), 4 waves,
// wave owns 16 q-rows, KVBLK=64. K/V staged via global_load_lds into
// XOR-swizzled [64][64] LDS, double-buffered, 1 barrier/tile.
// ---------------------------------------------------------------------------
__global__ __launch_bounds__(256) void attn_kernel(
    const __bf16* __restrict__ Q, const __bf16* __restrict__ K,
    const __bf16* __restrict__ Vt, __bf16* __restrict__ Attn)
{
    __shared__ __bf16 Ks[2][64][64];
    __shared__ __bf16 Vs[2][64][64];
    __shared__ __bf16 Ps[4][16][64];

    // bijective XCD swizzle: 768 blocks = 8 XCDs x 96
    const int bid = blockIdx.x;
    const int swz = (bid & 7) * 96 + (bid >> 3);
    const int h  = swz >> 6;          // 0..11
    const int q0 = (swz & 63) * 64;   // q-block start

    const int t = threadIdx.x, lane = t & 63, wid = t >> 6;
    const int lr = lane & 15, lc = lane >> 4;
    const int rl = lane >> 3;               // 0..7
    const int cs = (lane & 7) ^ rl;         // swizzled source chunk
    const int sx = lr & 7;                  // row-XOR for frag reads

    // per-lane staging source bases (advance by tile inside loop)
    const __bf16* kg = K  + (size_t)(wid * 16 + rl) * D_MODEL + h * HD + cs * 8;
    const __bf16* vg = Vt + (size_t)(h * HD + wid * 16 + rl) * SEQ + cs * 8;

    // Q fragments (B-operand), pre-scaled by QSCALE at projection
    const __bf16* qrow = Q + (size_t)(q0 + wid * 16 + lr) * D_MODEL + h * HD;
    bf16x8 qf0 = *(const bf16x8*)&qrow[lc * 8];
    bf16x8 qf1 = *(const bf16x8*)&qrow[32 + lc * 8];

    f32x4 acc[4] = {};               // O[q=lc*4+r][d=dt*16+lr]
    float m_r = -1e30f, l_r = 0.f;   // state for q-row = lr

    // prologue: stage tile 0 into buf 0
    {
        gload_lds16(kg,                 &Ks[0][wid * 16 + 0][0]);
        gload_lds16(kg + 8 * D_MODEL,   &Ks[0][wid * 16 + 8][0]);
        gload_lds16(vg,                 &Vs[0][wid * 16 + 0][0]);
        gload_lds16(vg + 8 * SEQ,       &Vs[0][wid * 16 + 8][0]);
    }

    const int NT = SEQ / 64;
    for (int kt = 0; kt < NT; ++kt) {
        const int cur = kt & 1;
        __syncthreads();   // drains vmcnt(0): tile kt landed; prev reads done

        // issue next tile into the other buffer (async DMA)
        if (kt + 1 < NT) {
            const int nxt = cur ^ 1;
            const size_t ko = (size_t)(kt + 1) * 64 * D_MODEL;
            const size_t vo = (size_t)(kt + 1) * 64;
            gload_lds16(kg + ko,               &Ks[nxt][wid * 16 + 0][0]);
            gload_lds16(kg + ko + 8 * D_MODEL, &Ks[nxt][wid * 16 + 8][0]);
            gload_lds16(vg + vo,               &Vs[nxt][wid * 16 + 0][0]);
            gload_lds16(vg + vo + 8 * SEQ,     &Vs[nxt][wid * 16 + 8][0]);
        }

        // S^T = K Q^T : lane holds S[kv=nt*16+lc*4+r][q=lr] (log2 domain)
        bf16x8 kf[4][2];
        #pragma unroll
        for (int nt = 0; nt < 4; ++nt) {
            kf[nt][0] = *(const bf16x8*)&Ks[cur][nt * 16 + lr][(lc ^ sx) * 8];
            kf[nt][1] = *(const bf16x8*)&Ks[cur][nt * 16 + lr][((4 | lc) ^ sx) * 8];
        }
        f32x4 st[4];
        __builtin_amdgcn_s_setprio(1);
        #pragma unroll
        for (int nt = 0; nt < 4; ++nt) {
            f32x4 s = {};
            s = __builtin_amdgcn_mfma_f32_16x16x32_bf16(kf[nt][0], qf0, s, 0, 0, 0);
            s = __builtin_amdgcn_mfma_f32_16x16x32_bf16(kf[nt][1], qf1, s, 0, 0, 0);
            st[nt] = s;
        }
        __builtin_amdgcn_s_setprio(0);

        // ---- online softmax (log2 domain), q-row = lr lane-local ----
        float mx = -1e30f;
        #pragma unroll
        for (int nt = 0; nt < 4; ++nt)
            #pragma unroll
            for (int r = 0; r < 4; ++r)
                mx = fmaxf(mx, st[nt][r]);
        mx = fmaxf(mx, __shfl_xor(mx, 16, 64));
        mx = fmaxf(mx, __shfl_xor(mx, 32, 64));

        const bool skip = (bool)__all(mx - m_r <= 8.0f);  // defer-max
        float mnew = skip ? m_r : fmaxf(m_r, mx);
        float corr = skip ? 1.0f : exp2f(m_r - mnew);

        float rs = 0.f;
        float pv[4][4];
        #pragma unroll
        for (int nt = 0; nt < 4; ++nt)
            #pragma unroll
            for (int r = 0; r < 4; ++r) {
                float p = exp2f(st[nt][r] - mnew);
                pv[nt][r] = p;
                rs += p;
            }
        rs += __shfl_xor(rs, 16, 64);
        rs += __shfl_xor(rs, 32, 64);
        l_r = l_r * corr + rs;
        m_r = mnew;

        if (!skip) {
            #pragma unroll
            for (int r = 0; r < 4; ++r) {
                float cq = __shfl(corr, lc * 4 + r, 64);
                #pragma unroll
                for (int dt = 0; dt < 4; ++dt)
                    acc[dt][r] *= cq;
            }
        }

        // P -> per-wave LDS, swizzled, one b64 write per nt
        #pragma unroll
        for (int nt = 0; nt < 4; ++nt) {
            union { __bf16 hh[4]; uint2 u; } w;
            w.hh[0] = (__bf16)pv[nt][0]; w.hh[1] = (__bf16)pv[nt][1];
            w.hh[2] = (__bf16)pv[nt][2]; w.hh[3] = (__bf16)pv[nt][3];
            const int pb = (((nt << 1) | (lc >> 1)) ^ sx) * 8 + (lc & 1) * 4;
            *(uint2*)&Ps[wid][lr][pb] = w.u;
        }

        // O += P V : A = P[q][kv], B = Vt[d][kv]
        bf16x8 pa0 = *(const bf16x8*)&Ps[wid][lr][(lc ^ sx) * 8];
        bf16x8 pa1 = *(const bf16x8*)&Ps[wid][lr][((4 | lc) ^ sx) * 8];
        __builtin_amdgcn_s_setprio(1);
        #pragma unroll
        for (int dt = 0; dt < 4; ++dt) {
            bf16x8 vf0 = *(const bf16x8*)&Vs[cur][dt * 16 + lr][(lc ^ sx) * 8];
            bf16x8 vf1 = *(const bf16x8*)&Vs[cur][dt * 16 + lr][((4 | lc) ^ sx) * 8];
            acc[dt] = __builtin_amdgcn_mfma_f32_16x16x32_bf16(pa0, vf0, acc[dt], 0, 0, 0);
            acc[dt] = __builtin_amdgcn_mfma_f32_16x16x32_bf16(pa1, vf1, acc[dt], 0, 0, 0);
        }
        __builtin_amdgcn_s_setprio(0);
    }

    // epilogue: O / l
    #pragma unroll
    for (int r = 0; r < 4; ++r) {
        float linv = 1.0f / __shfl(l_r, lc * 4 + r, 64);
        #pragma unroll
        for (int dt = 0; dt < 4; ++dt)
            Attn[(size_t)(q0 + wid * 16 + lc * 4 + r) * D_MODEL
                 + h * HD + dt * 16 + lr] = (__bf16)(acc[dt][r] * linv);
    }
}

// ---------------------------------------------------------------------------
// Kernel 3: output projection -> fp32 d_out
// ---------------------------------------------------------------------------
__global__ __launch_bounds__(256) void out_gemm(
    const __bf16* __restrict__ Ab, const __bf16* __restrict__ wob,
    const float* __restrict__ bo, float* __restrict__ out)
{
    __shared__ __bf16 As[128][64];
    __shared__ __bf16 Bs[128][64];
    const int bm = blockIdx.x, bn = blockIdx.y;
    f32x4 acc[4][4] = {};
    gemm128_core(Ab  + (size_t)bm * 128 * D_MODEL,
                 wob + (size_t)bn * 128 * D_MODEL, D_MODEL, acc, As, Bs);

    const int t = threadIdx.x, lane = t & 63, wid = t >> 6;
    const int wm = (wid & 1) * 64, wn = (wid >> 1) * 64;
    const int lr = lane & 15, lc = lane >> 4;
    const int m0 = bm * 128 + wm, n0 = bn * 128 + wn;
    #pragma unroll
    for (int mi = 0; mi < 4; ++mi)
        #pragma unroll
        for (int ni = 0; ni < 4; ++ni) {
            int col = n0 + ni * 16 + lr;
            float bb = bo[col];
            #pragma unroll
            for (int r = 0; r < 4; ++r)
                out[(size_t)(m0 + mi * 16 + lc * 4 + r) * D_MODEL + col] =
                    acc[mi][ni][r] + bb;
        }
}

// ---------------------------------------------------------------------------
extern "C" void kernel_launch(void* const* d_in, const int* in_sizes, int n_in,
                              void* d_out, int out_size, void* d_ws, size_t ws_size,
                              hipStream_t stream) {
    const float* x  = (const float*)d_in[0];
    const float* wq = (const float*)d_in[1];
    const float* bq = (const float*)d_in[2];
    const float* wk = (const float*)d_in[3];
    const float* bk = (const float*)d_in[4];
    const float* wv = (const float*)d_in[5];
    const float* bv = (const float*)d_in[6];
    const float* wo = (const float*)d_in[7];
    const float* bo = (const float*)d_in[8];

    char* ws = (char*)d_ws;
    const size_t XB_SZ = (size_t)SEQ * D_MODEL * 2;
    const size_t W_SZ  = (size_t)D_MODEL * D_MODEL * 2;
    __bf16* xb  = (__bf16*)(ws);
    __bf16* wqb = (__bf16*)(ws + XB_SZ);
    __bf16* wkb = (__bf16*)(ws + XB_SZ + W_SZ);
    __bf16* wvb = (__bf16*)(ws + XB_SZ + 2 * W_SZ);
    __bf16* wob = (__bf16*)(ws + XB_SZ + 3 * W_SZ);
    __bf16* Qb  = (__bf16*)(ws + XB_SZ + 4 * W_SZ);
    __bf16* Kb  = (__bf16*)(ws + 2 * XB_SZ + 4 * W_SZ);
    __bf16* Vtb = (__bf16*)(ws + 3 * XB_SZ + 4 * W_SZ);
    __bf16* Ab  = (__bf16*)(ws + 4 * XB_SZ + 4 * W_SZ);

    cvt_kernel<<<1024, 256, 0, stream>>>(x, wq, wk, wv, wo,
                                         xb, wqb, wkb, wvb, wob);
    qkv_gemm<<<dim3(32, 18), 256, 0, stream>>>(xb, wqb, wkb, wvb,
                                               bq, bk, bv, Qb, Kb, Vtb);
    attn_kernel<<<768, 256, 0, stream>>>(Qb, Kb, Vtb, Ab);
    out_gemm<<<dim3(32, 6), 256, 0, stream>>>(Ab, wob, bo, (float*)d_out);
}